// Round 2
// baseline (1043.332 us; speedup 1.0000x reference)
//
#include <hip/hip_runtime.h>
#include <cstdint>

// EarthAttention3D on gfx950 — f16 MFMA path.
// Stages: cvt x->f16 | transpose w's | bias_gather (dense bias into d_out scratch)
//         | QKV GEMM (mfma 16x16x32_f16, global_load_lds, dbuf+XCD swizzle)
//         | attention: one block per (b,w,h), no batch loop | proj GEMM.
// d_out doubles as bias_dense scratch (63.7 MB) — proj_gemm fully overwrites it.

typedef _Float16 f16;
typedef _Float16 f16x8 __attribute__((ext_vector_type(8)));
typedef _Float16 f16x4v __attribute__((ext_vector_type(4)));
typedef float f32x4 __attribute__((ext_vector_type(4)));

#define NW_ 64
#define HEADS_ 12
#define DIM_ 384
#define BATCH_ 15
#define NTOK_ 144
#define HD_ 32
#define MTOK_ (BATCH_*NW_*NTOK_)   // 138240
#define NWH_ (BATCH_*NW_*HEADS_)   // 11520
#define NMSQ_ (NTOK_*NTOK_)        // 20736

__device__ __forceinline__ void load16_lds(const void* g, void* l) {
    __builtin_amdgcn_global_load_lds(
        (const __attribute__((address_space(1))) uint32_t*)g,
        (__attribute__((address_space(3))) uint32_t*)l,
        16, 0, 0);
}

__device__ __forceinline__ f32x4 fzero4() {
    f32x4 z; z[0]=0.f; z[1]=0.f; z[2]=0.f; z[3]=0.f; return z;
}

// ---------------- pre-pass: fp32 -> f16 ----------------
__global__ void cvt_f32_to_f16(const float* __restrict__ src, f16* __restrict__ dst, int n4) {
    int i = blockIdx.x * blockDim.x + threadIdx.x;
    int stride = gridDim.x * blockDim.x;
    for (; i < n4; i += stride) {
        float4 v = ((const float4*)src)[i];
        f16x4v o;
        o[0] = (f16)v.x; o[1] = (f16)v.y; o[2] = (f16)v.z; o[3] = (f16)v.w;
        *(f16x4v*)(dst + 4*(size_t)i) = o;
    }
}

// src [K][N] fp32 -> dst [N][K] f16  (coalesced writes)
__global__ void transpose_cvt(const float* __restrict__ src, f16* __restrict__ dst, int K, int N) {
    int i = blockIdx.x * blockDim.x + threadIdx.x;
    if (i >= K*N) return;
    int n = i / K;
    int k = i - n*K;
    dst[i] = (f16)src[k*N + n];
}

// ---------------- bias gather: table[pos_idx[nm]][wh] -> dense[wh][nm] ----------------
// grid (768, 81): x = wh (consecutive blocks share the same 256 table rows -> L2 reuse),
// y = nm chunk of 256. Writes coalesced.
__global__ __launch_bounds__(256) void bias_gather(
    const float* __restrict__ bias_table, const int* __restrict__ pos_idx,
    float* __restrict__ dense)
{
    int wh = blockIdx.x;
    int nm = blockIdx.y * 256 + threadIdx.x;     // 81*256 = 20736 exact
    int idx = pos_idx[nm];
    dense[(size_t)wh*NMSQ_ + nm] = bias_table[(size_t)idx*(NW_*HEADS_) + wh];
}

// ---------------- QKV GEMM ----------------
// A: x_f16 [MTOK][384]; Bt: wt_qkv [1152][384] (= w_qkv^T).
// C[row][col] scattered: q[head][n][d], k[head][n][d], v[head][d][n]  (f16)
// Grid: 9720 linear blocks; XCD-chunked bijective swizzle (9720 = 8*1215),
// column index fastest within an XCD chunk so A row-panels are L2-reused 9x.
__global__ __launch_bounds__(256) void qkv_gemm(
    const f16* __restrict__ A, const f16* __restrict__ Bt,
    const float* __restrict__ bias,
    f16* __restrict__ qws, f16* __restrict__ kws, f16* __restrict__ vws)
{
    constexpr int BK = 32;
    constexpr int NT = DIM_/BK;  // 12 K-steps
    __shared__ __align__(16) f16 Asm[2][128*BK];
    __shared__ __align__(16) f16 Bsm[2][128*BK];
    const int tid  = threadIdx.x;
    const int lane = tid & 63;
    const int wave = tid >> 6;
    const int l15  = lane & 15;
    const int quad = lane >> 4;
    const int wr = wave >> 1, wc = wave & 1;

    unsigned lin = blockIdx.x;
    lin = (lin & 7u) * 1215u + (lin >> 3);   // XCD-chunked, bijective (9720 % 8 == 0)
    const int row0 = (int)(lin / 9u) * 128;
    const int col0 = (int)(lin % 9u) * 128;

    f32x4 acc[4][4];
    #pragma unroll
    for (int i = 0; i < 4; ++i)
        #pragma unroll
        for (int j = 0; j < 4; ++j) acc[i][j] = fzero4();

    auto stage = [&](int kt, int b) {
        const int k0 = kt * BK;
        #pragma unroll
        for (int cc = 0; cc < 2; ++cc) {
            int chunk  = wave*2 + cc;          // 0..7
            int flat16 = chunk*64 + lane;      // 16B units; r = /4, c16 = %4
            int r   = flat16 >> 2;
            int c16 = flat16 & 3;
            load16_lds(&A [(size_t)(row0 + r)*DIM_ + k0 + c16*8], (char*)(&Asm[b][0]) + chunk*1024);
            load16_lds(&Bt[(size_t)(col0 + r)*DIM_ + k0 + c16*8], (char*)(&Bsm[b][0]) + chunk*1024);
        }
    };
    auto compute = [&](int b) {
        f16x8 af[4], bf[4];
        #pragma unroll
        for (int i = 0; i < 4; ++i)
            af[i] = *(const f16x8*)&Asm[b][(wr*64 + i*16 + l15)*BK + quad*8];
        #pragma unroll
        for (int j = 0; j < 4; ++j)
            bf[j] = *(const f16x8*)&Bsm[b][(wc*64 + j*16 + l15)*BK + quad*8];
        #pragma unroll
        for (int i = 0; i < 4; ++i)
            #pragma unroll
            for (int j = 0; j < 4; ++j)
                acc[i][j] = __builtin_amdgcn_mfma_f32_16x16x32_f16(af[i], bf[j], acc[i][j], 0, 0, 0);
    };

    // 2-phase double-buffered pipeline: prefetch tile kt+1 while computing kt.
    stage(0, 0);
    asm volatile("s_waitcnt vmcnt(0)" ::: "memory");
    __builtin_amdgcn_s_barrier();
    __builtin_amdgcn_sched_barrier(0);
    int cur = 0;
    for (int kt = 0; kt < NT-1; ++kt) {
        stage(kt+1, cur^1);
        compute(cur);
        asm volatile("s_waitcnt vmcnt(0) lgkmcnt(0)" ::: "memory");
        __builtin_amdgcn_s_barrier();
        __builtin_amdgcn_sched_barrier(0);
        cur ^= 1;
    }
    compute(cur);

    // epilogue: col -> (which, h, d); row -> (bw, n)
    const int which = col0 / DIM_;     // block fully inside q, k, or v
    #pragma unroll
    for (int j = 0; j < 4; ++j) {
        int col = col0 + wc*64 + j*16 + l15;
        float bq = bias[col];
        int rem = col - which*DIM_;
        int h = rem >> 5, d = rem & 31;
        #pragma unroll
        for (int i = 0; i < 4; ++i) {
            int rowb = row0 + wr*64 + i*16 + quad*4;
            #pragma unroll
            for (int r = 0; r < 4; ++r) {
                int row = rowb + r;
                int bw  = row / NTOK_;
                int n   = row - bw*NTOK_;
                int head = bw*HEADS_ + h;
                f16 hv = (f16)(acc[i][j][r] + bq);
                if (which == 0)      qws[(size_t)head*NTOK_*HD_ + n*HD_ + d] = hv;
                else if (which == 1) kws[(size_t)head*NTOK_*HD_ + n*HD_ + d] = hv;
                else                 vws[(size_t)head*HD_*NTOK_ + d*NTOK_ + n] = hv;
            }
        }
    }
}

// ---------------- fused attention ----------------
// grid = 11520 blocks, one per (b, w, h); 576 threads = 9 waves (16 Q rows each).
// XCD-chunked swizzle keeps the 15 same-(w,h) blocks on one XCD (bias slice L2-hot).
__global__ __launch_bounds__(576) void attention(
    const f16* __restrict__ qws, const f16* __restrict__ kws, const f16* __restrict__ vws,
    const float* __restrict__ bias_dense,
    const float* __restrict__ mask, f16* __restrict__ ows)
{
    constexpr int KPAD = 40;   // Ksm row stride (f16)
    constexpr int VPAD = 168;  // Vt / P row stride (f16), 160 used (168: 2-way bank alias, free)
    // [Vt 10752B][ K 11520B overlaid by P strips 48384B ] = 59136 B
    __shared__ __align__(16) char smem[10752 + 48384];
    f16* Vt  = (f16*)smem;            // [32][168]
    f16* Ksm = (f16*)(smem + 10752);  // [144][40]
    f16* Pst = (f16*)(smem + 10752);  // [9][16][168]

    const int tid  = threadIdx.x;
    const int lane = tid & 63;
    const int wv   = tid >> 6;    // 0..8: Q row tile
    const int l15  = lane & 15;
    const int quad = lane >> 4;

    unsigned bid = blockIdx.x;
    unsigned lin = (bid & 7u) * 1440u + (bid >> 3);   // 11520 = 8*1440, bijective
    const int wh = (int)(lin / 15u);
    const int b  = (int)(lin - (unsigned)wh*15u);
    const int w  = wh / HEADS_;
    const int h  = wh - w*HEADS_;

    const int bwh = b*(NW_*HEADS_) + wh;
    const f16* qh = qws + (size_t)bwh*NTOK_*HD_;
    const f16* kh = kws + (size_t)bwh*NTOK_*HD_;
    const f16* vh = vws + (size_t)bwh*HD_*NTOK_;

    // zero Vt pad cols [144,160)
    if (tid < 64) {
        int d = tid >> 1, m0 = 144 + (tid & 1)*8;
        uint4 z = {0u,0u,0u,0u};
        *(uint4*)&Vt[d*VPAD + m0] = z;
    }

    // stage K [144][32]->Ksm[144][40] and V^T [32][144]->Vt[32][168]
    {
        int flat = tid*8;
        int n = flat >> 5, d = flat & 31;
        *(uint4*)&Ksm[n*KPAD + d] = *(const uint4*)&kh[flat];
        int dv = flat / NTOK_;
        int mv = flat - dv*NTOK_;
        *(uint4*)&Vt[dv*VPAD + mv] = *(const uint4*)&vh[flat];
    }
    // Q A-frag: row = l15, k = quad*8..+8
    const int nq = wv*16 + l15;
    f16x8 qf = *(const f16x8*)&qh[nq*HD_ + quad*8];

    // dense bias frags: n = wv*16+quad*4+r, m = j*16+l15  (direct L2 loads, no gather)
    const float* bd = bias_dense + (size_t)wh*NMSQ_;
    float brg[9][4];
    #pragma unroll
    for (int j = 0; j < 9; ++j) {
        int m = j*16 + l15;
        #pragma unroll
        for (int r = 0; r < 4; ++r)
            brg[j][r] = bd[(wv*16 + quad*4 + r)*NTOK_ + m];
    }

    __syncthreads();  // staging visible

    // S = Q K^T : 9 col tiles, one K=32 step each
    f32x4 sfr[9];
    #pragma unroll
    for (int j = 0; j < 9; ++j) {
        f16x8 kf = *(const f16x8*)&Ksm[(j*16 + l15)*KPAD + quad*8];
        sfr[j] = __builtin_amdgcn_mfma_f32_16x16x32_f16(qf, kf, fzero4(), 0, 0, 0);
    }
    __syncthreads();  // all K reads done; P strips may overwrite K region

    const float scale = 0.17677669529663687f;  // 32^-0.5

    // softmax over 144 cols (rows live in 16-lane groups); deferred normalization
    float p[9][4], rmax[4], rsum[4];
    #pragma unroll
    for (int r = 0; r < 4; ++r) rmax[r] = -1e30f;
    const float* mrow = mask + (size_t)b*NMSQ_;
    #pragma unroll
    for (int j = 0; j < 9; ++j) {
        int m = j*16 + l15;
        #pragma unroll
        for (int r = 0; r < 4; ++r) {
            int n = wv*16 + quad*4 + r;
            float s = sfr[j][r]*scale + brg[j][r] + mrow[n*NTOK_ + m];
            p[j][r] = s;
            rmax[r] = fmaxf(rmax[r], s);
        }
    }
    #pragma unroll
    for (int r = 0; r < 4; ++r) {
        float v = rmax[r];
        #pragma unroll
        for (int off = 1; off < 16; off <<= 1)
            v = fmaxf(v, __shfl_xor(v, off, 64));
        rmax[r] = v;
    }
    #pragma unroll
    for (int r = 0; r < 4; ++r) rsum[r] = 0.f;
    #pragma unroll
    for (int j = 0; j < 9; ++j)
        #pragma unroll
        for (int r = 0; r < 4; ++r) {
            float e = __expf(p[j][r] - rmax[r]);
            p[j][r] = e;
            rsum[r] += e;
        }
    #pragma unroll
    for (int r = 0; r < 4; ++r) {
        float v = rsum[r];
        #pragma unroll
        for (int off = 1; off < 16; off <<= 1)
            v += __shfl_xor(v, off, 64);
        rsum[r] = 1.0f / v;   // applied in epilogue
    }

    // write un-normalized P (C-layout) into own LDS strip; zero pad cols
    f16* Pw = Pst + wv*16*VPAD;
    #pragma unroll
    for (int j = 0; j < 9; ++j) {
        int m = j*16 + l15;
        #pragma unroll
        for (int r = 0; r < 4; ++r)
            Pw[(quad*4 + r)*VPAD + m] = (f16)p[j][r];
    }
    if (lane < 32) {
        int row = lane >> 1, m0 = 144 + (lane & 1)*8;
        uint4 z = {0u,0u,0u,0u};
        *(uint4*)&Pw[row*VPAD + m0] = z;
    }

    // O = P V : 5 K=32 steps (wave-local LDS round trip; no barrier needed)
    f32x4 o0 = fzero4(), o1 = fzero4();
    #pragma unroll
    for (int s = 0; s < 5; ++s) {
        f16x8 pa = *(const f16x8*)&Pw[l15*VPAD + s*32 + quad*8];
        f16x8 v0 = *(const f16x8*)&Vt[l15*VPAD + s*32 + quad*8];
        f16x8 v1 = *(const f16x8*)&Vt[(16 + l15)*VPAD + s*32 + quad*8];
        o0 = __builtin_amdgcn_mfma_f32_16x16x32_f16(pa, v0, o0, 0, 0, 0);
        o1 = __builtin_amdgcn_mfma_f32_16x16x32_f16(pa, v1, o1, 0, 0, 0);
    }

    // epilogue: O[n][d] -> ows[bw][n][h*32+d]  (f16), normalize by rsum here
    const int bw = b*NW_ + w;
    #pragma unroll
    for (int r = 0; r < 4; ++r) {
        int n = wv*16 + quad*4 + r;
        size_t base = ((size_t)bw*NTOK_ + n)*DIM_ + h*HD_;
        ows[base + l15]      = (f16)(o0[r]*rsum[r]);
        ows[base + 16 + l15] = (f16)(o1[r]*rsum[r]);
    }
}

// ---------------- proj GEMM ----------------
// A: o_f16 [MTOK][384]; Bt: wt_proj [384][384]; out fp32 [MTOK][384]
// Grid: 3240 linear blocks; XCD-chunked swizzle (3240 = 8*405), column fastest.
__global__ __launch_bounds__(256) void proj_gemm(
    const f16* __restrict__ A, const f16* __restrict__ Bt,
    const float* __restrict__ bias, float* __restrict__ out)
{
    constexpr int BK = 32;
    constexpr int NT = DIM_/BK;
    __shared__ __align__(16) f16 Asm[2][128*BK];
    __shared__ __align__(16) f16 Bsm[2][128*BK];
    const int tid  = threadIdx.x;
    const int lane = tid & 63;
    const int wave = tid >> 6;
    const int l15  = lane & 15;
    const int quad = lane >> 4;
    const int wr = wave >> 1, wc = wave & 1;

    unsigned lin = blockIdx.x;
    lin = (lin & 7u) * 405u + (lin >> 3);    // XCD-chunked, bijective (3240 % 8 == 0)
    const int row0 = (int)(lin / 3u) * 128;
    const int col0 = (int)(lin % 3u) * 128;

    f32x4 acc[4][4];
    #pragma unroll
    for (int i = 0; i < 4; ++i)
        #pragma unroll
        for (int j = 0; j < 4; ++j) acc[i][j] = fzero4();

    auto stage = [&](int kt, int b) {
        const int k0 = kt * BK;
        #pragma unroll
        for (int cc = 0; cc < 2; ++cc) {
            int chunk  = wave*2 + cc;
            int flat16 = chunk*64 + lane;
            int r   = flat16 >> 2;
            int c16 = flat16 & 3;
            load16_lds(&A [(size_t)(row0 + r)*DIM_ + k0 + c16*8], (char*)(&Asm[b][0]) + chunk*1024);
            load16_lds(&Bt[(size_t)(col0 + r)*DIM_ + k0 + c16*8], (char*)(&Bsm[b][0]) + chunk*1024);
        }
    };
    auto compute = [&](int b) {
        f16x8 af[4], bf[4];
        #pragma unroll
        for (int i = 0; i < 4; ++i)
            af[i] = *(const f16x8*)&Asm[b][(wr*64 + i*16 + l15)*BK + quad*8];
        #pragma unroll
        for (int j = 0; j < 4; ++j)
            bf[j] = *(const f16x8*)&Bsm[b][(wc*64 + j*16 + l15)*BK + quad*8];
        #pragma unroll
        for (int i = 0; i < 4; ++i)
            #pragma unroll
            for (int j = 0; j < 4; ++j)
                acc[i][j] = __builtin_amdgcn_mfma_f32_16x16x32_f16(af[i], bf[j], acc[i][j], 0, 0, 0);
    };

    stage(0, 0);
    asm volatile("s_waitcnt vmcnt(0)" ::: "memory");
    __builtin_amdgcn_s_barrier();
    __builtin_amdgcn_sched_barrier(0);
    int cur = 0;
    for (int kt = 0; kt < NT-1; ++kt) {
        stage(kt+1, cur^1);
        compute(cur);
        asm volatile("s_waitcnt vmcnt(0) lgkmcnt(0)" ::: "memory");
        __builtin_amdgcn_s_barrier();
        __builtin_amdgcn_sched_barrier(0);
        cur ^= 1;
    }
    compute(cur);

    #pragma unroll
    for (int j = 0; j < 4; ++j) {
        int col = col0 + wc*64 + j*16 + l15;
        float bp = bias[col];
        #pragma unroll
        for (int i = 0; i < 4; ++i) {
            int rowb = row0 + wr*64 + i*16 + quad*4;
            #pragma unroll
            for (int r = 0; r < 4; ++r)
                out[(size_t)(rowb + r)*DIM_ + col] = acc[i][j][r] + bp;
        }
    }
}

// ---------------- launcher ----------------
extern "C" void kernel_launch(void* const* d_in, const int* in_sizes, int n_in,
                              void* d_out, int out_size, void* d_ws, size_t ws_size,
                              hipStream_t stream)
{
    const float* x      = (const float*)d_in[0];
    const float* mask   = (const float*)d_in[1];
    const float* w_qkv  = (const float*)d_in[2];
    const float* b_qkv  = (const float*)d_in[3];
    const float* w_proj = (const float*)d_in[4];
    const float* b_proj = (const float*)d_in[5];
    const float* btab   = (const float*)d_in[6];
    const int*   pidx   = (const int*)d_in[7];
    float* out = (float*)d_out;

    constexpr size_t X16_B = (size_t)MTOK_*DIM_*2;        // 106,168,320
    constexpr size_t WTQ_B = (size_t)1152*384*2;          // 884,736
    constexpr size_t WTP_B = (size_t)384*384*2;           // 294,912
    constexpr size_t HEAD_B = (size_t)NWH_*NTOK_*HD_*2;   // 106,168,320

    char* ws = (char*)d_ws;
    f16* x16 = (f16*)ws;
    f16* wtq = (f16*)(ws + X16_B);
    f16* wtp = (f16*)(ws + X16_B + WTQ_B);
    f16* qws = (f16*)(ws + X16_B + WTQ_B + WTP_B);
    f16* kws = (f16*)((char*)qws + HEAD_B);
    f16* vws = (f16*)((char*)kws + HEAD_B);
    f16* ows = x16;  // x_f16 is dead after qkv_gemm; reuse for attention output

    // bias_dense lives in d_out (63.7 MB of the 212 MB output buffer);
    // consumed by attention, then proj_gemm fully overwrites d_out.
    float* bias_dense = (float*)d_out;

    cvt_f32_to_f16<<<8192, 256, 0, stream>>>(x, x16, MTOK_*DIM_/4);
    transpose_cvt<<<(384*1152 + 255)/256, 256, 0, stream>>>(w_qkv, wtq, 384, 1152);
    transpose_cvt<<<(384*384  + 255)/256, 256, 0, stream>>>(w_proj, wtp, 384, 384);
    bias_gather<<<dim3(NW_*HEADS_, NMSQ_/256), 256, 0, stream>>>(btab, pidx, bias_dense);
    qkv_gemm<<<9720, 256, 0, stream>>>(x16, wtq, b_qkv, qws, kws, vws);
    attention<<<NWH_, 576, 0, stream>>>(qws, kws, vws, bias_dense, mask, ows);
    proj_gemm<<<3240, 256, 0, stream>>>(ows, wtp, b_proj, out);
}

// Round 3
// 1034.824 us; speedup vs baseline: 1.0082x; 1.0082x over previous
//
#include <hip/hip_runtime.h>
#include <cstdint>

// EarthAttention3D on gfx950 — f16 MFMA path.
// Stages: cvt x->f16 | transpose w's | bias_gather (dense bias into d_out scratch)
//         | QKV GEMM | attention (one block per (b,w,h)) | proj GEMM.
// This rev (GEMMs): depth-2 prefetch pipeline, 3 LDS buffers, counted s_waitcnt
// vmcnt(4) (loads stay in flight across barriers), and LDS bank-conflict swizzle
// via pre-swizzled global source (slot ^= (row>>1)&3; LDS linear, read swizzled).

typedef _Float16 f16;
typedef _Float16 f16x8 __attribute__((ext_vector_type(8)));
typedef _Float16 f16x4v __attribute__((ext_vector_type(4)));
typedef float f32x4 __attribute__((ext_vector_type(4)));

#define NW_ 64
#define HEADS_ 12
#define DIM_ 384
#define BATCH_ 15
#define NTOK_ 144
#define HD_ 32
#define MTOK_ (BATCH_*NW_*NTOK_)   // 138240
#define NWH_ (BATCH_*NW_*HEADS_)   // 11520
#define NMSQ_ (NTOK_*NTOK_)        // 20736

__device__ __forceinline__ void load16_lds(const void* g, void* l) {
    __builtin_amdgcn_global_load_lds(
        (const __attribute__((address_space(1))) uint32_t*)g,
        (__attribute__((address_space(3))) uint32_t*)l,
        16, 0, 0);
}

__device__ __forceinline__ f32x4 fzero4() {
    f32x4 z; z[0]=0.f; z[1]=0.f; z[2]=0.f; z[3]=0.f; return z;
}

// ---------------- pre-pass: fp32 -> f16 ----------------
__global__ void cvt_f32_to_f16(const float* __restrict__ src, f16* __restrict__ dst, int n4) {
    int i = blockIdx.x * blockDim.x + threadIdx.x;
    int stride = gridDim.x * blockDim.x;
    for (; i < n4; i += stride) {
        float4 v = ((const float4*)src)[i];
        f16x4v o;
        o[0] = (f16)v.x; o[1] = (f16)v.y; o[2] = (f16)v.z; o[3] = (f16)v.w;
        *(f16x4v*)(dst + 4*(size_t)i) = o;
    }
}

// src [K][N] fp32 -> dst [N][K] f16  (coalesced writes)
__global__ void transpose_cvt(const float* __restrict__ src, f16* __restrict__ dst, int K, int N) {
    int i = blockIdx.x * blockDim.x + threadIdx.x;
    if (i >= K*N) return;
    int n = i / K;
    int k = i - n*K;
    dst[i] = (f16)src[k*N + n];
}

// ---------------- bias gather: table[pos_idx[nm]][wh] -> dense[wh][nm] ----------------
__global__ __launch_bounds__(256) void bias_gather(
    const float* __restrict__ bias_table, const int* __restrict__ pos_idx,
    float* __restrict__ dense)
{
    int wh = blockIdx.x;
    int nm = blockIdx.y * 256 + threadIdx.x;     // 81*256 = 20736 exact
    int idx = pos_idx[nm];
    dense[(size_t)wh*NMSQ_ + nm] = bias_table[(size_t)idx*(NW_*HEADS_) + wh];
}

// ---------------- QKV GEMM ----------------
// A: x_f16 [MTOK][384]; Bt: wt_qkv [1152][384].  128x128 tile, BK=32, 12 K-steps.
// Depth-2 counted-vmcnt pipeline over 3 LDS buffers; bank-swizzled staging.
__global__ __launch_bounds__(256) void qkv_gemm(
    const f16* __restrict__ A, const f16* __restrict__ Bt,
    const float* __restrict__ bias,
    f16* __restrict__ qws, f16* __restrict__ kws, f16* __restrict__ vws)
{
    constexpr int BK = 32;
    constexpr int NT = DIM_/BK;  // 12
    __shared__ __align__(16) f16 Asm[3][128*BK];
    __shared__ __align__(16) f16 Bsm[3][128*BK];
    const int tid  = threadIdx.x;
    const int lane = tid & 63;
    const int wave = tid >> 6;
    const int l15  = lane & 15;
    const int quad = lane >> 4;
    const int wr = wave >> 1, wc = wave & 1;

    unsigned lin = blockIdx.x;
    lin = (lin & 7u) * 1215u + (lin >> 3);   // XCD-chunked, bijective (9720 % 8 == 0)
    const int row0 = (int)(lin / 9u) * 128;
    const int col0 = (int)(lin % 9u) * 128;

    f32x4 acc[4][4];
    #pragma unroll
    for (int i = 0; i < 4; ++i)
        #pragma unroll
        for (int j = 0; j < 4; ++j) acc[i][j] = fzero4();

    // LDS[r][s] (16B slots s=0..3) holds global slot s ^ ((r>>1)&3); dest linear.
    auto stage = [&](int kt, int b) {
        const int k0 = kt * BK;
        #pragma unroll
        for (int cc = 0; cc < 2; ++cc) {
            int chunk  = wave*2 + cc;          // 0..7
            int flat16 = chunk*64 + lane;      // 16B units
            int r   = flat16 >> 2;
            int c16 = flat16 & 3;
            int cs  = c16 ^ ((r >> 1) & 3);    // pre-swizzled global slot
            load16_lds(&A [(size_t)(row0 + r)*DIM_ + k0 + cs*8], (char*)(&Asm[b][0]) + chunk*1024);
            load16_lds(&Bt[(size_t)(col0 + r)*DIM_ + k0 + cs*8], (char*)(&Bsm[b][0]) + chunk*1024);
        }
    };
    auto compute = [&](int b) {
        f16x8 af[4], bf[4];
        #pragma unroll
        for (int i = 0; i < 4; ++i) {
            int row = wr*64 + i*16 + l15;
            int s   = quad ^ ((row >> 1) & 3);
            af[i] = *(const f16x8*)&Asm[b][row*BK + s*8];
        }
        #pragma unroll
        for (int j = 0; j < 4; ++j) {
            int row = wc*64 + j*16 + l15;
            int s   = quad ^ ((row >> 1) & 3);
            bf[j] = *(const f16x8*)&Bsm[b][row*BK + s*8];
        }
        #pragma unroll
        for (int i = 0; i < 4; ++i)
            #pragma unroll
            for (int j = 0; j < 4; ++j)
                acc[i][j] = __builtin_amdgcn_mfma_f32_16x16x32_f16(af[i], bf[j], acc[i][j], 0, 0, 0);
    };

    // depth-2 pipeline: 4 loads/thread per stage; vmcnt(4) leaves next stage in flight.
    stage(0, 0);
    stage(1, 1);
    #pragma unroll
    for (int kt = 0; kt < NT-2; ++kt) {
        asm volatile("s_waitcnt vmcnt(4) lgkmcnt(0)" ::: "memory");
        __builtin_amdgcn_s_barrier();
        __builtin_amdgcn_sched_barrier(0);
        stage(kt+2, (kt+2)%3);
        compute(kt%3);
    }
    asm volatile("s_waitcnt vmcnt(4) lgkmcnt(0)" ::: "memory");
    __builtin_amdgcn_s_barrier();
    __builtin_amdgcn_sched_barrier(0);
    compute((NT-2)%3);
    asm volatile("s_waitcnt vmcnt(0) lgkmcnt(0)" ::: "memory");
    __builtin_amdgcn_s_barrier();
    __builtin_amdgcn_sched_barrier(0);
    compute((NT-1)%3);

    // epilogue: col -> (which, h, d); row -> (bw, n)
    const int which = col0 / DIM_;     // block fully inside q, k, or v
    #pragma unroll
    for (int j = 0; j < 4; ++j) {
        int col = col0 + wc*64 + j*16 + l15;
        float bq = bias[col];
        int rem = col - which*DIM_;
        int h = rem >> 5, d = rem & 31;
        #pragma unroll
        for (int i = 0; i < 4; ++i) {
            int rowb = row0 + wr*64 + i*16 + quad*4;
            #pragma unroll
            for (int r = 0; r < 4; ++r) {
                int row = rowb + r;
                int bw  = row / NTOK_;
                int n   = row - bw*NTOK_;
                int head = bw*HEADS_ + h;
                f16 hv = (f16)(acc[i][j][r] + bq);
                if (which == 0)      qws[(size_t)head*NTOK_*HD_ + n*HD_ + d] = hv;
                else if (which == 1) kws[(size_t)head*NTOK_*HD_ + n*HD_ + d] = hv;
                else                 vws[(size_t)head*HD_*NTOK_ + d*NTOK_ + n] = hv;
            }
        }
    }
}

// ---------------- fused attention ----------------
// grid = 11520 blocks, one per (b, w, h); 576 threads = 9 waves (16 Q rows each).
__global__ __launch_bounds__(576) void attention(
    const f16* __restrict__ qws, const f16* __restrict__ kws, const f16* __restrict__ vws,
    const float* __restrict__ bias_dense,
    const float* __restrict__ mask, f16* __restrict__ ows)
{
    constexpr int KPAD = 40;   // Ksm row stride (f16)
    constexpr int VPAD = 168;  // Vt / P row stride (f16), 160 used
    __shared__ __align__(16) char smem[10752 + 48384];
    f16* Vt  = (f16*)smem;            // [32][168]
    f16* Ksm = (f16*)(smem + 10752);  // [144][40]
    f16* Pst = (f16*)(smem + 10752);  // [9][16][168]

    const int tid  = threadIdx.x;
    const int lane = tid & 63;
    const int wv   = tid >> 6;    // 0..8: Q row tile
    const int l15  = lane & 15;
    const int quad = lane >> 4;

    unsigned bid = blockIdx.x;
    unsigned lin = (bid & 7u) * 1440u + (bid >> 3);   // 11520 = 8*1440, bijective
    const int wh = (int)(lin / 15u);
    const int b  = (int)(lin - (unsigned)wh*15u);
    const int w  = wh / HEADS_;
    const int h  = wh - w*HEADS_;

    const int bwh = b*(NW_*HEADS_) + wh;
    const f16* qh = qws + (size_t)bwh*NTOK_*HD_;
    const f16* kh = kws + (size_t)bwh*NTOK_*HD_;
    const f16* vh = vws + (size_t)bwh*HD_*NTOK_;

    if (tid < 64) {
        int d = tid >> 1, m0 = 144 + (tid & 1)*8;
        uint4 z = {0u,0u,0u,0u};
        *(uint4*)&Vt[d*VPAD + m0] = z;
    }

    {   // stage K [144][32]->Ksm[144][40] and V^T [32][144]->Vt[32][168]
        int flat = tid*8;
        int n = flat >> 5, d = flat & 31;
        *(uint4*)&Ksm[n*KPAD + d] = *(const uint4*)&kh[flat];
        int dv = flat / NTOK_;
        int mv = flat - dv*NTOK_;
        *(uint4*)&Vt[dv*VPAD + mv] = *(const uint4*)&vh[flat];
    }
    const int nq = wv*16 + l15;
    f16x8 qf = *(const f16x8*)&qh[nq*HD_ + quad*8];

    const float* bd = bias_dense + (size_t)wh*NMSQ_;
    float brg[9][4];
    #pragma unroll
    for (int j = 0; j < 9; ++j) {
        int m = j*16 + l15;
        #pragma unroll
        for (int r = 0; r < 4; ++r)
            brg[j][r] = bd[(wv*16 + quad*4 + r)*NTOK_ + m];
    }

    __syncthreads();  // staging visible

    f32x4 sfr[9];
    #pragma unroll
    for (int j = 0; j < 9; ++j) {
        f16x8 kf = *(const f16x8*)&Ksm[(j*16 + l15)*KPAD + quad*8];
        sfr[j] = __builtin_amdgcn_mfma_f32_16x16x32_f16(qf, kf, fzero4(), 0, 0, 0);
    }
    __syncthreads();  // all K reads done; P strips may overwrite K region

    const float scale = 0.17677669529663687f;  // 32^-0.5

    float p[9][4], rmax[4], rsum[4];
    #pragma unroll
    for (int r = 0; r < 4; ++r) rmax[r] = -1e30f;
    const float* mrow = mask + (size_t)b*NMSQ_;
    #pragma unroll
    for (int j = 0; j < 9; ++j) {
        int m = j*16 + l15;
        #pragma unroll
        for (int r = 0; r < 4; ++r) {
            int n = wv*16 + quad*4 + r;
            float s = sfr[j][r]*scale + brg[j][r] + mrow[n*NTOK_ + m];
            p[j][r] = s;
            rmax[r] = fmaxf(rmax[r], s);
        }
    }
    #pragma unroll
    for (int r = 0; r < 4; ++r) {
        float v = rmax[r];
        #pragma unroll
        for (int off = 1; off < 16; off <<= 1)
            v = fmaxf(v, __shfl_xor(v, off, 64));
        rmax[r] = v;
    }
    #pragma unroll
    for (int r = 0; r < 4; ++r) rsum[r] = 0.f;
    #pragma unroll
    for (int j = 0; j < 9; ++j)
        #pragma unroll
        for (int r = 0; r < 4; ++r) {
            float e = __expf(p[j][r] - rmax[r]);
            p[j][r] = e;
            rsum[r] += e;
        }
    #pragma unroll
    for (int r = 0; r < 4; ++r) {
        float v = rsum[r];
        #pragma unroll
        for (int off = 1; off < 16; off <<= 1)
            v += __shfl_xor(v, off, 64);
        rsum[r] = 1.0f / v;   // applied in epilogue
    }

    f16* Pw = Pst + wv*16*VPAD;
    #pragma unroll
    for (int j = 0; j < 9; ++j) {
        int m = j*16 + l15;
        #pragma unroll
        for (int r = 0; r < 4; ++r)
            Pw[(quad*4 + r)*VPAD + m] = (f16)p[j][r];
    }
    if (lane < 32) {
        int row = lane >> 1, m0 = 144 + (lane & 1)*8;
        uint4 z = {0u,0u,0u,0u};
        *(uint4*)&Pw[row*VPAD + m0] = z;
    }

    f32x4 o0 = fzero4(), o1 = fzero4();
    #pragma unroll
    for (int s = 0; s < 5; ++s) {
        f16x8 pa = *(const f16x8*)&Pw[l15*VPAD + s*32 + quad*8];
        f16x8 v0 = *(const f16x8*)&Vt[l15*VPAD + s*32 + quad*8];
        f16x8 v1 = *(const f16x8*)&Vt[(16 + l15)*VPAD + s*32 + quad*8];
        o0 = __builtin_amdgcn_mfma_f32_16x16x32_f16(pa, v0, o0, 0, 0, 0);
        o1 = __builtin_amdgcn_mfma_f32_16x16x32_f16(pa, v1, o1, 0, 0, 0);
    }

    const int bw = b*NW_ + w;
    #pragma unroll
    for (int r = 0; r < 4; ++r) {
        int n = wv*16 + quad*4 + r;
        size_t base = ((size_t)bw*NTOK_ + n)*DIM_ + h*HD_;
        ows[base + l15]      = (f16)(o0[r]*rsum[r]);
        ows[base + 16 + l15] = (f16)(o1[r]*rsum[r]);
    }
}

// ---------------- proj GEMM ----------------
// A: o_f16 [MTOK][384]; Bt: wt_proj [384][384]; out fp32 [MTOK][384]
__global__ __launch_bounds__(256) void proj_gemm(
    const f16* __restrict__ A, const f16* __restrict__ Bt,
    const float* __restrict__ bias, float* __restrict__ out)
{
    constexpr int BK = 32;
    constexpr int NT = DIM_/BK;
    __shared__ __align__(16) f16 Asm[3][128*BK];
    __shared__ __align__(16) f16 Bsm[3][128*BK];
    const int tid  = threadIdx.x;
    const int lane = tid & 63;
    const int wave = tid >> 6;
    const int l15  = lane & 15;
    const int quad = lane >> 4;
    const int wr = wave >> 1, wc = wave & 1;

    unsigned lin = blockIdx.x;
    lin = (lin & 7u) * 405u + (lin >> 3);    // XCD-chunked, bijective (3240 % 8 == 0)
    const int row0 = (int)(lin / 3u) * 128;
    const int col0 = (int)(lin % 3u) * 128;

    f32x4 acc[4][4];
    #pragma unroll
    for (int i = 0; i < 4; ++i)
        #pragma unroll
        for (int j = 0; j < 4; ++j) acc[i][j] = fzero4();

    auto stage = [&](int kt, int b) {
        const int k0 = kt * BK;
        #pragma unroll
        for (int cc = 0; cc < 2; ++cc) {
            int chunk  = wave*2 + cc;
            int flat16 = chunk*64 + lane;
            int r   = flat16 >> 2;
            int c16 = flat16 & 3;
            int cs  = c16 ^ ((r >> 1) & 3);
            load16_lds(&A [(size_t)(row0 + r)*DIM_ + k0 + cs*8], (char*)(&Asm[b][0]) + chunk*1024);
            load16_lds(&Bt[(size_t)(col0 + r)*DIM_ + k0 + cs*8], (char*)(&Bsm[b][0]) + chunk*1024);
        }
    };
    auto compute = [&](int b) {
        f16x8 af[4], bf[4];
        #pragma unroll
        for (int i = 0; i < 4; ++i) {
            int row = wr*64 + i*16 + l15;
            int s   = quad ^ ((row >> 1) & 3);
            af[i] = *(const f16x8*)&Asm[b][row*BK + s*8];
        }
        #pragma unroll
        for (int j = 0; j < 4; ++j) {
            int row = wc*64 + j*16 + l15;
            int s   = quad ^ ((row >> 1) & 3);
            bf[j] = *(const f16x8*)&Bsm[b][row*BK + s*8];
        }
        #pragma unroll
        for (int i = 0; i < 4; ++i)
            #pragma unroll
            for (int j = 0; j < 4; ++j)
                acc[i][j] = __builtin_amdgcn_mfma_f32_16x16x32_f16(af[i], bf[j], acc[i][j], 0, 0, 0);
    };

    stage(0, 0);
    stage(1, 1);
    #pragma unroll
    for (int kt = 0; kt < NT-2; ++kt) {
        asm volatile("s_waitcnt vmcnt(4) lgkmcnt(0)" ::: "memory");
        __builtin_amdgcn_s_barrier();
        __builtin_amdgcn_sched_barrier(0);
        stage(kt+2, (kt+2)%3);
        compute(kt%3);
    }
    asm volatile("s_waitcnt vmcnt(4) lgkmcnt(0)" ::: "memory");
    __builtin_amdgcn_s_barrier();
    __builtin_amdgcn_sched_barrier(0);
    compute((NT-2)%3);
    asm volatile("s_waitcnt vmcnt(0) lgkmcnt(0)" ::: "memory");
    __builtin_amdgcn_s_barrier();
    __builtin_amdgcn_sched_barrier(0);
    compute((NT-1)%3);

    #pragma unroll
    for (int j = 0; j < 4; ++j) {
        int col = col0 + wc*64 + j*16 + l15;
        float bp = bias[col];
        #pragma unroll
        for (int i = 0; i < 4; ++i) {
            int rowb = row0 + wr*64 + i*16 + quad*4;
            #pragma unroll
            for (int r = 0; r < 4; ++r)
                out[(size_t)(rowb + r)*DIM_ + col] = acc[i][j][r] + bp;
        }
    }
}

// ---------------- launcher ----------------
extern "C" void kernel_launch(void* const* d_in, const int* in_sizes, int n_in,
                              void* d_out, int out_size, void* d_ws, size_t ws_size,
                              hipStream_t stream)
{
    const float* x      = (const float*)d_in[0];
    const float* mask   = (const float*)d_in[1];
    const float* w_qkv  = (const float*)d_in[2];
    const float* b_qkv  = (const float*)d_in[3];
    const float* w_proj = (const float*)d_in[4];
    const float* b_proj = (const float*)d_in[5];
    const float* btab   = (const float*)d_in[6];
    const int*   pidx   = (const int*)d_in[7];
    float* out = (float*)d_out;

    constexpr size_t X16_B = (size_t)MTOK_*DIM_*2;        // 106,168,320
    constexpr size_t WTQ_B = (size_t)1152*384*2;          // 884,736
    constexpr size_t WTP_B = (size_t)384*384*2;           // 294,912
    constexpr size_t HEAD_B = (size_t)NWH_*NTOK_*HD_*2;   // 106,168,320

    char* ws = (char*)d_ws;
    f16* x16 = (f16*)ws;
    f16* wtq = (f16*)(ws + X16_B);
    f16* wtp = (f16*)(ws + X16_B + WTQ_B);
    f16* qws = (f16*)(ws + X16_B + WTQ_B + WTP_B);
    f16* kws = (f16*)((char*)qws + HEAD_B);
    f16* vws = (f16*)((char*)kws + HEAD_B);
    f16* ows = x16;  // x_f16 is dead after qkv_gemm; reuse for attention output

    // bias_dense lives in d_out (63.7 MB of the 212 MB output buffer);
    // consumed by attention, then proj_gemm fully overwrites d_out.
    float* bias_dense = (float*)d_out;

    cvt_f32_to_f16<<<8192, 256, 0, stream>>>(x, x16, MTOK_*DIM_/4);
    transpose_cvt<<<(384*1152 + 255)/256, 256, 0, stream>>>(w_qkv, wtq, 384, 1152);
    transpose_cvt<<<(384*384  + 255)/256, 256, 0, stream>>>(w_proj, wtp, 384, 384);
    bias_gather<<<dim3(NW_*HEADS_, NMSQ_/256), 256, 0, stream>>>(btab, pidx, bias_dense);
    qkv_gemm<<<9720, 256, 0, stream>>>(x16, wtq, b_qkv, qws, kws, vws);
    attention<<<NWH_, 576, 0, stream>>>(qws, kws, vws, bias_dense, mask, ows);
    proj_gemm<<<3240, 256, 0, stream>>>(ows, wtp, b_proj, out);
}